// Round 1
// baseline (515.029 us; speedup 1.0000x reference)
//
#include <hip/hip_runtime.h>
#include <hip/hip_bf16.h>

// AttentionBlock: x(2,512,64,64) fp32 -> GN(32 groups) -> QKV(1536x512) ->
// 8-head attention (L=4096, ch=64) -> proj(512x512) -> +x.
// All GEMM/attention math in bf16 MFMA (16x16x32), fp32 accumulate.

typedef __attribute__((ext_vector_type(8))) short bf16x8;
typedef __attribute__((ext_vector_type(4))) float f32x4;

#define LL 4096
#define CC 512

__device__ __forceinline__ ushort f2bf(float f) {
    union { float f; unsigned u; } v; v.f = f;
    unsigned u = v.u;
    u += 0x7fffu + ((u >> 16) & 1u);   // round-to-nearest-even
    return (ushort)(u >> 16);
}

// ---------------- K0: fp32 weights -> bf16 ----------------
__global__ __launch_bounds__(256) void k_convert(
        const float* __restrict__ qkv_w, const float* __restrict__ proj_w,
        ushort* __restrict__ wq, ushort* __restrict__ wp) {
    const int NQ = 1536 * 512;
    int base = (blockIdx.x * 256 + threadIdx.x) * 4;
    const float* src; ushort* dst; int off;
    if (base < NQ) { src = qkv_w; dst = wq; off = base; }
    else           { src = proj_w; dst = wp; off = base - NQ; }
    float4 v = *reinterpret_cast<const float4*>(src + off);
    ushort4 o;
    o.x = f2bf(v.x); o.y = f2bf(v.y); o.z = f2bf(v.z); o.w = f2bf(v.w);
    *reinterpret_cast<ushort4*>(dst + off) = o;
}

// ---------------- K1a: GN partial sums ----------------
// grid (64 bg, 8 slices); each group = 16ch x 4096 = 65536 floats
__global__ __launch_bounds__(256) void k_gn_part(
        const float* __restrict__ x, float2* __restrict__ part) {
    int bg = blockIdx.x, sl = blockIdx.y;
    const float4* xg = reinterpret_cast<const float4*>(x + (size_t)bg * 65536) + sl * 2048;
    float s = 0.f, ss = 0.f;
    for (int i = threadIdx.x; i < 2048; i += 256) {
        float4 v = xg[i];
        s  += v.x + v.y + v.z + v.w;
        ss += v.x*v.x + v.y*v.y + v.z*v.z + v.w*v.w;
    }
    #pragma unroll
    for (int m = 32; m; m >>= 1) { s += __shfl_xor(s, m); ss += __shfl_xor(ss, m); }
    __shared__ float red[8];
    int wid = threadIdx.x >> 6;
    if ((threadIdx.x & 63) == 0) { red[wid*2] = s; red[wid*2+1] = ss; }
    __syncthreads();
    if (threadIdx.x == 0) {
        s  = red[0] + red[2] + red[4] + red[6];
        ss = red[1] + red[3] + red[5] + red[7];
        part[bg * 8 + sl] = make_float2(s, ss);
    }
}

// ---------------- K1b: finalize stats ----------------
__global__ void k_gn_stats(const float2* __restrict__ part, float2* __restrict__ stats) {
    int i = threadIdx.x;  // 0..63
    float s = 0.f, ss = 0.f;
    #pragma unroll
    for (int j = 0; j < 8; ++j) { float2 p = part[i*8 + j]; s += p.x; ss += p.y; }
    float mean = s * (1.f/65536.f);
    float var  = ss * (1.f/65536.f) - mean*mean;
    stats[i] = make_float2(mean, rsqrtf(var + 1e-5f));
}

// ---------------- K1c: apply GN, write hid as (b, l, c) bf16 ----------------
// grid (16 l-chunks, 64 bg). LDS transpose so global writes are 32B/lane.
__global__ __launch_bounds__(256) void k_gn_apply(
        const float* __restrict__ x, const float* __restrict__ gamma,
        const float* __restrict__ beta, const float2* __restrict__ stats,
        ushort* __restrict__ hid) {
    int bg = blockIdx.y;
    int b = bg >> 5, c0 = (bg & 31) * 16;
    int l0 = blockIdx.x * 256;
    float2 st = stats[bg];
    __shared__ __align__(16) ushort tile[16][256];
    int tid = threadIdx.x;
    const float* xg = x + (size_t)(b * CC + c0) * LL;
    #pragma unroll
    for (int sub = 0; sub < 4; ++sub) {
        int r = sub * 4 + (tid >> 6);
        int c4 = (tid & 63) * 4;
        float4 v = *reinterpret_cast<const float4*>(xg + (size_t)r * LL + l0 + c4);
        float ga = gamma[c0 + r] * st.y;
        float be = beta[c0 + r] - st.x * ga;
        tile[r][c4+0] = f2bf(v.x * ga + be);
        tile[r][c4+1] = f2bf(v.y * ga + be);
        tile[r][c4+2] = f2bf(v.z * ga + be);
        tile[r][c4+3] = f2bf(v.w * ga + be);
    }
    __syncthreads();
    union { ushort u[16]; uint4 q[2]; } pk;
    #pragma unroll
    for (int r = 0; r < 16; ++r) pk.u[r] = tile[r][tid];
    ushort* dst = hid + ((size_t)b * LL + l0 + tid) * CC + c0;
    *reinterpret_cast<uint4*>(dst)     = pk.q[0];
    *reinterpret_cast<uint4*>(dst + 8) = pk.q[1];
}

// ---------------- K2: QKV GEMM ----------------
// D[o][l] = sum_c wq[o][c] * hid[l][c], o in [0,1536). 128x128 tile, BK=32.
// o = head*192 + part*64 + ch. Q,K written (bh,l,64); V written (bh,64,l).
// Q gets the exact *0.125 fold (scale^2 of ch^-0.25).
__global__ __launch_bounds__(256) void k_qkv(
        const ushort* __restrict__ wq, const ushort* __restrict__ hid,
        const float* __restrict__ qkv_b,
        ushort* __restrict__ q_ws, ushort* __restrict__ k_ws, ushort* __restrict__ v_ws) {
    int b = blockIdx.z;
    int n0 = blockIdx.x * 128;
    int m0 = blockIdx.y * 128;
    int tid = threadIdx.x;
    int w = tid >> 6, lane = tid & 63, h = lane >> 4, lm = lane & 15;
    int m0w = (w & 1) * 64, n0w = (w >> 1) * 64;
    __shared__ __align__(16) ushort As[128][40];
    __shared__ __align__(16) ushort Bs[128][40];
    f32x4 acc[4][4] = {};
    const ushort* Ag = wq + (size_t)m0 * CC;
    const ushort* Bg = hid + (size_t)(b * LL + n0) * CC;
    for (int k0 = 0; k0 < CC; k0 += 32) {
        __syncthreads();
        #pragma unroll
        for (int i = 0; i < 2; ++i) {
            int flat = tid + i * 256;
            int row = flat >> 2, ch = (flat & 3) * 8;
            *reinterpret_cast<uint4*>(&As[row][ch]) =
                *reinterpret_cast<const uint4*>(Ag + (size_t)row * CC + k0 + ch);
            *reinterpret_cast<uint4*>(&Bs[row][ch]) =
                *reinterpret_cast<const uint4*>(Bg + (size_t)row * CC + k0 + ch);
        }
        __syncthreads();
        bf16x8 af[4], bfr[4];
        #pragma unroll
        for (int mi = 0; mi < 4; ++mi)
            af[mi] = *reinterpret_cast<const bf16x8*>(&As[m0w + mi*16 + lm][h*8]);
        #pragma unroll
        for (int nj = 0; nj < 4; ++nj)
            bfr[nj] = *reinterpret_cast<const bf16x8*>(&Bs[n0w + nj*16 + lm][h*8]);
        #pragma unroll
        for (int mi = 0; mi < 4; ++mi)
            #pragma unroll
            for (int nj = 0; nj < 4; ++nj)
                acc[mi][nj] = __builtin_amdgcn_mfma_f32_16x16x32_bf16(af[mi], bfr[nj], acc[mi][nj], 0, 0, 0);
    }
    #pragma unroll
    for (int mi = 0; mi < 4; ++mi) {
        int o_base = m0 + m0w + mi * 16 + h * 4;       // 4-aligned, never crosses 64-blocks
        float4 bias = *reinterpret_cast<const float4*>(qkv_b + o_base);
        int head = o_base / 192;
        int rem  = o_base - head * 192;
        int part = rem >> 6;
        int ch   = rem & 63;
        #pragma unroll
        for (int nj = 0; nj < 4; ++nj) {
            int l = n0 + n0w + nj * 16 + lm;
            float v0 = acc[mi][nj][0] + bias.x;
            float v1 = acc[mi][nj][1] + bias.y;
            float v2 = acc[mi][nj][2] + bias.z;
            float v3 = acc[mi][nj][3] + bias.w;
            if (part == 0) {
                ushort4 pk;
                pk.x = f2bf(v0 * 0.125f); pk.y = f2bf(v1 * 0.125f);
                pk.z = f2bf(v2 * 0.125f); pk.w = f2bf(v3 * 0.125f);
                *reinterpret_cast<ushort4*>(q_ws + ((size_t)(b*8 + head) * LL + l) * 64 + ch) = pk;
            } else if (part == 1) {
                ushort4 pk;
                pk.x = f2bf(v0); pk.y = f2bf(v1); pk.z = f2bf(v2); pk.w = f2bf(v3);
                *reinterpret_cast<ushort4*>(k_ws + ((size_t)(b*8 + head) * LL + l) * 64 + ch) = pk;
            } else {
                ushort* vp = v_ws + ((size_t)(b*8 + head) * 64 + ch) * LL + l;
                vp[0] = f2bf(v0); vp[LL] = f2bf(v1); vp[2*LL] = f2bf(v2); vp[3*LL] = f2bf(v3);
            }
        }
    }
}

// ---------------- K3: flash attention ----------------
// grid (64 q-blocks, 16 bh); 4 waves/block, wave handles 16 queries, BS=64.
// Q,K read as (bh,l,64) -> K-contiguous fragments; V read as (bh,64,l).
// P re-shaped D-frag -> A-frag through per-wave padded LDS (no barriers).
__global__ __launch_bounds__(256) void k_attn(
        const ushort* __restrict__ q_ws, const ushort* __restrict__ k_ws,
        const ushort* __restrict__ v_ws, ushort* __restrict__ o_ws) {
    int bh = blockIdx.y;
    int tid = threadIdx.x;
    int w = tid >> 6, lane = tid & 63, h = lane >> 4, lm = lane & 15;
    int t0 = blockIdx.x * 64 + w * 16;
    __shared__ __align__(16) ushort P[4][16][72];   // +8 pad vs 64: 2-way banks on b128 reads
    const ushort* qp = q_ws + ((size_t)bh * LL + t0 + lm) * 64 + h * 8;
    bf16x8 aQ0 = *reinterpret_cast<const bf16x8*>(qp);
    bf16x8 aQ1 = *reinterpret_cast<const bf16x8*>(qp + 32);
    float mr[4] = {-1e30f, -1e30f, -1e30f, -1e30f};
    float lr[4] = {0.f, 0.f, 0.f, 0.f};
    f32x4 accO[4] = {};
    const ushort* kb = k_ws + ((size_t)bh * LL + lm) * 64 + h * 8;
    const ushort* vb = v_ws + ((size_t)bh * 64 + lm) * LL + h * 8;
    for (int s0 = 0; s0 < LL; s0 += 64) {
        f32x4 sf[4];
        #pragma unroll
        for (int ss = 0; ss < 4; ++ss) {
            const ushort* kp = kb + (size_t)(s0 + ss * 16) * 64;
            f32x4 z = {0.f, 0.f, 0.f, 0.f};
            z      = __builtin_amdgcn_mfma_f32_16x16x32_bf16(aQ0, *reinterpret_cast<const bf16x8*>(kp),      z, 0, 0, 0);
            sf[ss] = __builtin_amdgcn_mfma_f32_16x16x32_bf16(aQ1, *reinterpret_cast<const bf16x8*>(kp + 32), z, 0, 0, 0);
        }
        float tmax[4], rsum[4], corr[4];
        #pragma unroll
        for (int r = 0; r < 4; ++r)
            tmax[r] = fmaxf(fmaxf(sf[0][r], sf[1][r]), fmaxf(sf[2][r], sf[3][r]));
        #pragma unroll
        for (int m = 1; m < 16; m <<= 1)
            #pragma unroll
            for (int r = 0; r < 4; ++r)
                tmax[r] = fmaxf(tmax[r], __shfl_xor(tmax[r], m));
        #pragma unroll
        for (int r = 0; r < 4; ++r) {
            float mn = fmaxf(mr[r], tmax[r]);
            corr[r] = __expf(mr[r] - mn);
            mr[r] = mn;
        }
        #pragma unroll
        for (int ss = 0; ss < 4; ++ss)
            #pragma unroll
            for (int r = 0; r < 4; ++r)
                sf[ss][r] = __expf(sf[ss][r] - mr[r]);
        #pragma unroll
        for (int r = 0; r < 4; ++r)
            rsum[r] = sf[0][r] + sf[1][r] + sf[2][r] + sf[3][r];
        #pragma unroll
        for (int m = 1; m < 16; m <<= 1)
            #pragma unroll
            for (int r = 0; r < 4; ++r)
                rsum[r] += __shfl_xor(rsum[r], m);
        #pragma unroll
        for (int r = 0; r < 4; ++r)
            lr[r] = lr[r] * corr[r] + rsum[r];
        #pragma unroll
        for (int nj = 0; nj < 4; ++nj)
            #pragma unroll
            for (int r = 0; r < 4; ++r)
                accO[nj][r] *= corr[r];
        // P (D-frag layout) -> LDS -> A-frag layout. Same-wave LDS is in-order.
        #pragma unroll
        for (int ss = 0; ss < 4; ++ss)
            #pragma unroll
            for (int r = 0; r < 4; ++r)
                P[w][h * 4 + r][ss * 16 + lm] = f2bf(sf[ss][r]);
        bf16x8 aP0 = *reinterpret_cast<const bf16x8*>(&P[w][lm][h * 8]);
        bf16x8 aP1 = *reinterpret_cast<const bf16x8*>(&P[w][lm][32 + h * 8]);
        #pragma unroll
        for (int nj = 0; nj < 4; ++nj) {
            const ushort* vp = vb + (size_t)nj * 16 * LL + s0;
            accO[nj] = __builtin_amdgcn_mfma_f32_16x16x32_bf16(aP0, *reinterpret_cast<const bf16x8*>(vp),      accO[nj], 0, 0, 0);
            accO[nj] = __builtin_amdgcn_mfma_f32_16x16x32_bf16(aP1, *reinterpret_cast<const bf16x8*>(vp + 32), accO[nj], 0, 0, 0);
        }
    }
    float inv[4];
    #pragma unroll
    for (int r = 0; r < 4; ++r) inv[r] = 1.f / lr[r];
    #pragma unroll
    for (int nj = 0; nj < 4; ++nj)
        #pragma unroll
        for (int r = 0; r < 4; ++r)
            o_ws[((size_t)bh * LL + t0 + h * 4 + r) * 64 + nj * 16 + lm] = f2bf(accO[nj][r] * inv[r]);
}

// ---------------- K4: proj GEMM + bias + residual ----------------
// out[b][o][l] = x + proj_b[o] + sum_c wp[o][c] * a[c][l],
// a stored as o_ws[bh][l][64] with c = head*64+ch.
__global__ __launch_bounds__(256) void k_proj(
        const ushort* __restrict__ wp, const ushort* __restrict__ o_ws,
        const float* __restrict__ proj_b, const float* __restrict__ x,
        float* __restrict__ out) {
    int b = blockIdx.z;
    int n0 = blockIdx.x * 128;
    int m0 = blockIdx.y * 128;
    int tid = threadIdx.x;
    int w = tid >> 6, lane = tid & 63, h = lane >> 4, lm = lane & 15;
    int m0w = (w & 1) * 64, n0w = (w >> 1) * 64;
    __shared__ __align__(16) ushort As[128][40];
    __shared__ __align__(16) ushort Bs[128][40];
    f32x4 acc[4][4] = {};
    const ushort* Ag = wp + (size_t)m0 * CC;
    for (int k0 = 0; k0 < CC; k0 += 32) {
        const ushort* Bg = o_ws + ((size_t)(b * 8 + (k0 >> 6)) * LL + n0) * 64 + (k0 & 63);
        __syncthreads();
        #pragma unroll
        for (int i = 0; i < 2; ++i) {
            int flat = tid + i * 256;
            int row = flat >> 2, ch = (flat & 3) * 8;
            *reinterpret_cast<uint4*>(&As[row][ch]) =
                *reinterpret_cast<const uint4*>(Ag + (size_t)row * CC + k0 + ch);
            *reinterpret_cast<uint4*>(&Bs[row][ch]) =
                *reinterpret_cast<const uint4*>(Bg + (size_t)row * 64 + ch);
        }
        __syncthreads();
        bf16x8 af[4], bfr[4];
        #pragma unroll
        for (int mi = 0; mi < 4; ++mi)
            af[mi] = *reinterpret_cast<const bf16x8*>(&As[m0w + mi*16 + lm][h*8]);
        #pragma unroll
        for (int nj = 0; nj < 4; ++nj)
            bfr[nj] = *reinterpret_cast<const bf16x8*>(&Bs[n0w + nj*16 + lm][h*8]);
        #pragma unroll
        for (int mi = 0; mi < 4; ++mi)
            #pragma unroll
            for (int nj = 0; nj < 4; ++nj)
                acc[mi][nj] = __builtin_amdgcn_mfma_f32_16x16x32_bf16(af[mi], bfr[nj], acc[mi][nj], 0, 0, 0);
    }
    #pragma unroll
    for (int mi = 0; mi < 4; ++mi) {
        int o = m0 + m0w + mi * 16 + h * 4;
        float4 bias = *reinterpret_cast<const float4*>(proj_b + o);
        #pragma unroll
        for (int nj = 0; nj < 4; ++nj) {
            int l = n0 + n0w + nj * 16 + lm;
            size_t xo = (size_t)(b * CC + o) * LL + l;
            out[xo]          = acc[mi][nj][0] + bias.x + x[xo];
            out[xo +   LL]   = acc[mi][nj][1] + bias.y + x[xo +   LL];
            out[xo + 2*LL]   = acc[mi][nj][2] + bias.z + x[xo + 2*LL];
            out[xo + 3*LL]   = acc[mi][nj][3] + bias.w + x[xo + 3*LL];
        }
    }
}

extern "C" void kernel_launch(void* const* d_in, const int* in_sizes, int n_in,
                              void* d_out, int out_size, void* d_ws, size_t ws_size,
                              hipStream_t stream) {
    const float* x      = (const float*)d_in[0];
    const float* norm_w = (const float*)d_in[1];
    const float* norm_b = (const float*)d_in[2];
    const float* qkv_w  = (const float*)d_in[3];
    const float* qkv_b  = (const float*)d_in[4];
    const float* proj_w = (const float*)d_in[5];
    const float* proj_b = (const float*)d_in[6];
    float* out = (float*)d_out;
    char* ws = (char*)d_ws;

    // ws layout (bytes): all buffers fully written before read each call.
    ushort* wq    = (ushort*)(ws);                         // 1536*512 bf16
    ushort* wp    = (ushort*)(ws + 1572864);               // 512*512 bf16
    ushort* hid   = (ushort*)(ws + 2097152);               // (2,4096,512) bf16
    ushort* q_ws  = (ushort*)(ws + 10485760);              // (16,4096,64) bf16
    ushort* k_ws  = (ushort*)(ws + 18874368);              // (16,4096,64) bf16
    ushort* v_ws  = (ushort*)(ws + 27262976);              // (16,64,4096) bf16
    ushort* o_ws  = (ushort*)(ws + 35651584);              // (16,4096,64) bf16
    float2* part  = (float2*)(ws + 44040192);              // 64*8 float2
    float2* stats = (float2*)(ws + 44044288);              // 64 float2

    k_convert<<<dim3(1024), dim3(256), 0, stream>>>(qkv_w, proj_w, wq, wp);
    k_gn_part<<<dim3(64, 8), dim3(256), 0, stream>>>(x, part);
    k_gn_stats<<<dim3(1), dim3(64), 0, stream>>>(part, stats);
    k_gn_apply<<<dim3(16, 64), dim3(256), 0, stream>>>(x, norm_w, norm_b, stats, hid);
    k_qkv<<<dim3(32, 12, 2), dim3(256), 0, stream>>>(wq, hid, qkv_b, q_ws, k_ws, v_ws);
    k_attn<<<dim3(64, 16), dim3(256), 0, stream>>>(q_ws, k_ws, v_ws, o_ws);
    k_proj<<<dim3(32, 4, 2), dim3(256), 0, stream>>>(wp, o_ws, proj_b, x, out);
}

// Round 2
// 225.631 us; speedup vs baseline: 2.2826x; 2.2826x over previous
//
#include <hip/hip_runtime.h>
#include <hip/hip_bf16.h>

// AttentionBlock: x(2,512,64,64) fp32 -> GN(32 groups) -> QKV(1536x512) ->
// 8-head attention (L=4096, ch=64) -> proj(512x512) -> +x.
// All GEMM/attention math in bf16 MFMA (16x16x32), fp32 accumulate.

typedef __attribute__((ext_vector_type(8))) short bf16x8;
typedef __attribute__((ext_vector_type(4))) float f32x4;

#define LL 4096
#define CC 512

__device__ __forceinline__ ushort f2bf(float f) {
    union { float f; unsigned u; } v; v.f = f;
    unsigned u = v.u;
    u += 0x7fffu + ((u >> 16) & 1u);   // round-to-nearest-even
    return (ushort)(u >> 16);
}

// DPP rotate within 16-lane row (VALU-rate cross-lane, avoids LDS-pipe ds_swizzle)
template<int CTRL>
__device__ __forceinline__ float row_ror(float x) {
    int xi = __float_as_int(x);
    int r = __builtin_amdgcn_update_dpp(xi, xi, CTRL, 0xF, 0xF, false);
    return __int_as_float(r);
}

// ---------------- K0: fp32 weights -> bf16 ----------------
__global__ __launch_bounds__(256) void k_convert(
        const float* __restrict__ qkv_w, const float* __restrict__ proj_w,
        ushort* __restrict__ wq, ushort* __restrict__ wp) {
    const int NQ = 1536 * 512;
    int base = (blockIdx.x * 256 + threadIdx.x) * 4;
    const float* src; ushort* dst; int off;
    if (base < NQ) { src = qkv_w; dst = wq; off = base; }
    else           { src = proj_w; dst = wp; off = base - NQ; }
    float4 v = *reinterpret_cast<const float4*>(src + off);
    ushort4 o;
    o.x = f2bf(v.x); o.y = f2bf(v.y); o.z = f2bf(v.z); o.w = f2bf(v.w);
    *reinterpret_cast<ushort4*>(dst + off) = o;
}

// ---------------- K1a: GN partial sums ----------------
__global__ __launch_bounds__(256) void k_gn_part(
        const float* __restrict__ x, float2* __restrict__ part) {
    int bg = blockIdx.x, sl = blockIdx.y;
    const float4* xg = reinterpret_cast<const float4*>(x + (size_t)bg * 65536) + sl * 2048;
    float s = 0.f, ss = 0.f;
    for (int i = threadIdx.x; i < 2048; i += 256) {
        float4 v = xg[i];
        s  += v.x + v.y + v.z + v.w;
        ss += v.x*v.x + v.y*v.y + v.z*v.z + v.w*v.w;
    }
    #pragma unroll
    for (int m = 32; m; m >>= 1) { s += __shfl_xor(s, m); ss += __shfl_xor(ss, m); }
    __shared__ float red[8];
    int wid = threadIdx.x >> 6;
    if ((threadIdx.x & 63) == 0) { red[wid*2] = s; red[wid*2+1] = ss; }
    __syncthreads();
    if (threadIdx.x == 0) {
        s  = red[0] + red[2] + red[4] + red[6];
        ss = red[1] + red[3] + red[5] + red[7];
        part[bg * 8 + sl] = make_float2(s, ss);
    }
}

// ---------------- K1b: finalize stats ----------------
__global__ void k_gn_stats(const float2* __restrict__ part, float2* __restrict__ stats) {
    int i = threadIdx.x;  // 0..63
    float s = 0.f, ss = 0.f;
    #pragma unroll
    for (int j = 0; j < 8; ++j) { float2 p = part[i*8 + j]; s += p.x; ss += p.y; }
    float mean = s * (1.f/65536.f);
    float var  = ss * (1.f/65536.f) - mean*mean;
    stats[i] = make_float2(mean, rsqrtf(var + 1e-5f));
}

// ---------------- K1c: apply GN, write hid as (b, l, c) bf16 ----------------
__global__ __launch_bounds__(256) void k_gn_apply(
        const float* __restrict__ x, const float* __restrict__ gamma,
        const float* __restrict__ beta, const float2* __restrict__ stats,
        ushort* __restrict__ hid) {
    int bg = blockIdx.y;
    int b = bg >> 5, c0 = (bg & 31) * 16;
    int l0 = blockIdx.x * 256;
    float2 st = stats[bg];
    __shared__ __align__(16) ushort tile[16][256];
    int tid = threadIdx.x;
    const float* xg = x + (size_t)(b * CC + c0) * LL;
    #pragma unroll
    for (int sub = 0; sub < 4; ++sub) {
        int r = sub * 4 + (tid >> 6);
        int c4 = (tid & 63) * 4;
        float4 v = *reinterpret_cast<const float4*>(xg + (size_t)r * LL + l0 + c4);
        float ga = gamma[c0 + r] * st.y;
        float be = beta[c0 + r] - st.x * ga;
        tile[r][c4+0] = f2bf(v.x * ga + be);
        tile[r][c4+1] = f2bf(v.y * ga + be);
        tile[r][c4+2] = f2bf(v.z * ga + be);
        tile[r][c4+3] = f2bf(v.w * ga + be);
    }
    __syncthreads();
    union { ushort u[16]; uint4 q[2]; } pk;
    #pragma unroll
    for (int r = 0; r < 16; ++r) pk.u[r] = tile[r][tid];
    ushort* dst = hid + ((size_t)b * LL + l0 + tid) * CC + c0;
    *reinterpret_cast<uint4*>(dst)     = pk.q[0];
    *reinterpret_cast<uint4*>(dst + 8) = pk.q[1];
}

// ---------------- K2: QKV GEMM ----------------
__global__ __launch_bounds__(256) void k_qkv(
        const ushort* __restrict__ wq, const ushort* __restrict__ hid,
        const float* __restrict__ qkv_b,
        ushort* __restrict__ q_ws, ushort* __restrict__ k_ws, ushort* __restrict__ v_ws) {
    int b = blockIdx.z;
    int n0 = blockIdx.x * 128;
    int m0 = blockIdx.y * 128;
    int tid = threadIdx.x;
    int w = tid >> 6, lane = tid & 63, h = lane >> 4, lm = lane & 15;
    int m0w = (w & 1) * 64, n0w = (w >> 1) * 64;
    __shared__ __align__(16) ushort As[128][40];
    __shared__ __align__(16) ushort Bs[128][40];
    f32x4 acc[4][4] = {};
    const ushort* Ag = wq + (size_t)m0 * CC;
    const ushort* Bg = hid + (size_t)(b * LL + n0) * CC;
    for (int k0 = 0; k0 < CC; k0 += 32) {
        __syncthreads();
        #pragma unroll
        for (int i = 0; i < 2; ++i) {
            int flat = tid + i * 256;
            int row = flat >> 2, ch = (flat & 3) * 8;
            *reinterpret_cast<uint4*>(&As[row][ch]) =
                *reinterpret_cast<const uint4*>(Ag + (size_t)row * CC + k0 + ch);
            *reinterpret_cast<uint4*>(&Bs[row][ch]) =
                *reinterpret_cast<const uint4*>(Bg + (size_t)row * CC + k0 + ch);
        }
        __syncthreads();
        bf16x8 af[4], bfr[4];
        #pragma unroll
        for (int mi = 0; mi < 4; ++mi)
            af[mi] = *reinterpret_cast<const bf16x8*>(&As[m0w + mi*16 + lm][h*8]);
        #pragma unroll
        for (int nj = 0; nj < 4; ++nj)
            bfr[nj] = *reinterpret_cast<const bf16x8*>(&Bs[n0w + nj*16 + lm][h*8]);
        #pragma unroll
        for (int mi = 0; mi < 4; ++mi)
            #pragma unroll
            for (int nj = 0; nj < 4; ++nj)
                acc[mi][nj] = __builtin_amdgcn_mfma_f32_16x16x32_bf16(af[mi], bfr[nj], acc[mi][nj], 0, 0, 0);
    }
    #pragma unroll
    for (int mi = 0; mi < 4; ++mi) {
        int o_base = m0 + m0w + mi * 16 + h * 4;
        float4 bias = *reinterpret_cast<const float4*>(qkv_b + o_base);
        int head = o_base / 192;
        int rem  = o_base - head * 192;
        int part = rem >> 6;
        int ch   = rem & 63;
        #pragma unroll
        for (int nj = 0; nj < 4; ++nj) {
            int l = n0 + n0w + nj * 16 + lm;
            float v0 = acc[mi][nj][0] + bias.x;
            float v1 = acc[mi][nj][1] + bias.y;
            float v2 = acc[mi][nj][2] + bias.z;
            float v3 = acc[mi][nj][3] + bias.w;
            if (part == 0) {
                ushort4 pk;
                pk.x = f2bf(v0 * 0.125f); pk.y = f2bf(v1 * 0.125f);
                pk.z = f2bf(v2 * 0.125f); pk.w = f2bf(v3 * 0.125f);
                *reinterpret_cast<ushort4*>(q_ws + ((size_t)(b*8 + head) * LL + l) * 64 + ch) = pk;
            } else if (part == 1) {
                ushort4 pk;
                pk.x = f2bf(v0); pk.y = f2bf(v1); pk.z = f2bf(v2); pk.w = f2bf(v3);
                *reinterpret_cast<ushort4*>(k_ws + ((size_t)(b*8 + head) * LL + l) * 64 + ch) = pk;
            } else {
                ushort* vp = v_ws + ((size_t)(b*8 + head) * 64 + ch) * LL + l;
                vp[0] = f2bf(v0); vp[LL] = f2bf(v1); vp[2*LL] = f2bf(v2); vp[3*LL] = f2bf(v3);
            }
        }
    }
}

// ---------------- K3: flash attention v2 ----------------
// grid (32 q-blocks, 16 bh); 4 waves/block; wave owns 32 queries (2 q-tiles).
// K,V(transposed) staged in shared LDS (padded rows, double-buffered,
// reg-staged: loads for t+1 issued before the barrier -> latency hides under
// compute of t). Softmax row-max via DPP row_ror (no LDS-pipe shuffles);
// row-sum via a ones-row appended to V^T so PV's MFMA accumulates the
// denominator with exact online-softmax rescaling. One barrier per step.
__global__ __launch_bounds__(256) void k_attn(
        const ushort* __restrict__ q_ws, const ushort* __restrict__ k_ws,
        const ushort* __restrict__ v_ws, ushort* __restrict__ o_ws) {
    int bh = blockIdx.y;
    int tid = threadIdx.x;
    int w = tid >> 6, lane = tid & 63, h = lane >> 4, lm = lane & 15;
    int t0 = blockIdx.x * 128 + w * 32;

    __shared__ __align__(16) ushort Ks [2][64][72];   // [kv][c], stride 144B: uniform banks
    __shared__ __align__(16) ushort Vts[2][80][72];   // [d][kv]; rows 64..79: ones row + zeros
    __shared__ __align__(16) ushort Ps [4][32][72];   // per-wave P tile [q][kv]

    // ones/zero rows of V^T (row 64 = 1.0 -> PV accumulates row-sum into nj=4 tile)
    for (int i = tid; i < 2 * 16 * 72; i += 256) {
        int pp = i / 1152, rem = i % 1152, rr = rem / 72, cc = rem % 72;
        Vts[pp][64 + rr][cc] = (rr == 0) ? (ushort)0x3F80 : (ushort)0;
    }

    // Q fragments in registers (A-operand): q rows = t0+qt*16+lm, k = kc*32+h*8
    bf16x8 aQ[2][2];
    {
        const ushort* qp = q_ws + ((size_t)bh * LL + t0 + lm) * 64 + h * 8;
        aQ[0][0] = *reinterpret_cast<const bf16x8*>(qp);
        aQ[0][1] = *reinterpret_cast<const bf16x8*>(qp + 32);
        aQ[1][0] = *reinterpret_cast<const bf16x8*>(qp + 16 * 64);
        aQ[1][1] = *reinterpret_cast<const bf16x8*>(qp + 16 * 64 + 32);
    }

    int srow = lane >> 3, scol = (lane & 7) * 8;   // staging: 16 rows/wave, 16B chunks
    uint4 kr0, kr1, vr0, vr1;
    auto issue = [&](int t) {
        const ushort* kg = k_ws + ((size_t)bh * LL + t * 64 + w * 16 + srow) * 64 + scol;
        kr0 = *reinterpret_cast<const uint4*>(kg);
        kr1 = *reinterpret_cast<const uint4*>(kg + 8 * 64);
        const ushort* vg = v_ws + ((size_t)bh * 64 + w * 16 + srow) * LL + t * 64 + scol;
        vr0 = *reinterpret_cast<const uint4*>(vg);
        vr1 = *reinterpret_cast<const uint4*>(vg + 8 * LL);
    };
    issue(0);

    float mr[2][4] = {{-1e30f,-1e30f,-1e30f,-1e30f},{-1e30f,-1e30f,-1e30f,-1e30f}};
    f32x4 accO[2][5] = {};   // nj=4 tile: softmax denominator (ones column)

    for (int t = 0; t < 64; ++t) {
        int p = t & 1;
        {   // commit staged tile t into buf p
            int row = w * 16 + srow;
            *reinterpret_cast<uint4*>(&Ks [p][row    ][scol]) = kr0;
            *reinterpret_cast<uint4*>(&Ks [p][row + 8][scol]) = kr1;
            *reinterpret_cast<uint4*>(&Vts[p][row    ][scol]) = vr0;
            *reinterpret_cast<uint4*>(&Vts[p][row + 8][scol]) = vr1;
        }
        if (t < 63) issue(t + 1);   // in flight across the whole compute phase
        __syncthreads();

        // ---- QK^T: S[32q][64kv], K frag reused across both q-tiles ----
        f32x4 sf[2][4] = {};
        __builtin_amdgcn_s_setprio(1);
        #pragma unroll
        for (int ss = 0; ss < 4; ++ss)
            #pragma unroll
            for (int kc = 0; kc < 2; ++kc) {
                bf16x8 bK = *reinterpret_cast<const bf16x8*>(&Ks[p][ss*16 + lm][kc*32 + h*8]);
                sf[0][ss] = __builtin_amdgcn_mfma_f32_16x16x32_bf16(aQ[0][kc], bK, sf[0][ss], 0, 0, 0);
                sf[1][ss] = __builtin_amdgcn_mfma_f32_16x16x32_bf16(aQ[1][kc], bK, sf[1][ss], 0, 0, 0);
            }
        __builtin_amdgcn_s_setprio(0);

        // ---- online softmax: DPP max over the 16-lane kv axis ----
        float corr[2][4];
        #pragma unroll
        for (int qt = 0; qt < 2; ++qt)
            #pragma unroll
            for (int r = 0; r < 4; ++r) {
                float tm = fmaxf(fmaxf(sf[qt][0][r], sf[qt][1][r]),
                                 fmaxf(sf[qt][2][r], sf[qt][3][r]));
                tm = fmaxf(tm, row_ror<0x121>(tm));
                tm = fmaxf(tm, row_ror<0x122>(tm));
                tm = fmaxf(tm, row_ror<0x124>(tm));
                tm = fmaxf(tm, row_ror<0x128>(tm));
                float mn = fmaxf(mr[qt][r], tm);
                corr[qt][r] = __expf(mr[qt][r] - mn);
                mr[qt][r] = mn;
                #pragma unroll
                for (int ss = 0; ss < 4; ++ss)
                    sf[qt][ss][r] = __expf(sf[qt][ss][r] - mn);
            }

        // P -> per-wave LDS (same-wave readback, no barrier)
        #pragma unroll
        for (int qt = 0; qt < 2; ++qt)
            #pragma unroll
            for (int ss = 0; ss < 4; ++ss)
                #pragma unroll
                for (int r = 0; r < 4; ++r)
                    Ps[w][qt*16 + h*4 + r][ss*16 + lm] = f2bf(sf[qt][ss][r]);

        // rescale O (incl. denominator tile)
        #pragma unroll
        for (int qt = 0; qt < 2; ++qt)
            #pragma unroll
            for (int nj = 0; nj < 5; ++nj)
                #pragma unroll
                for (int r = 0; r < 4; ++r)
                    accO[qt][nj][r] *= corr[qt][r];

        // ---- PV: V frag reused across both q-tiles; nj=4 = ones row ----
        __builtin_amdgcn_s_setprio(1);
        #pragma unroll
        for (int kc = 0; kc < 2; ++kc) {
            bf16x8 aP0 = *reinterpret_cast<const bf16x8*>(&Ps[w][     lm][kc*32 + h*8]);
            bf16x8 aP1 = *reinterpret_cast<const bf16x8*>(&Ps[w][16 + lm][kc*32 + h*8]);
            #pragma unroll
            for (int nj = 0; nj < 5; ++nj) {
                bf16x8 bV = *reinterpret_cast<const bf16x8*>(&Vts[p][nj*16 + lm][kc*32 + h*8]);
                accO[0][nj] = __builtin_amdgcn_mfma_f32_16x16x32_bf16(aP0, bV, accO[0][nj], 0, 0, 0);
                accO[1][nj] = __builtin_amdgcn_mfma_f32_16x16x32_bf16(aP1, bV, accO[1][nj], 0, 0, 0);
            }
        }
        __builtin_amdgcn_s_setprio(0);
    }

    // epilogue: denominator lives in col lm==0 of the nj=4 tile -> broadcast
    #pragma unroll
    for (int qt = 0; qt < 2; ++qt)
        #pragma unroll
        for (int r = 0; r < 4; ++r) {
            float l  = __shfl(accO[qt][4][r], lane & 48);
            float iv = 1.f / l;
            #pragma unroll
            for (int nj = 0; nj < 4; ++nj)
                o_ws[((size_t)bh * LL + t0 + qt*16 + h*4 + r) * 64 + nj*16 + lm] =
                    f2bf(accO[qt][nj][r] * iv);
        }
}

// ---------------- K4: proj GEMM + bias + residual ----------------
__global__ __launch_bounds__(256) void k_proj(
        const ushort* __restrict__ wp, const ushort* __restrict__ o_ws,
        const float* __restrict__ proj_b, const float* __restrict__ x,
        float* __restrict__ out) {
    int b = blockIdx.z;
    int n0 = blockIdx.x * 128;
    int m0 = blockIdx.y * 128;
    int tid = threadIdx.x;
    int w = tid >> 6, lane = tid & 63, h = lane >> 4, lm = lane & 15;
    int m0w = (w & 1) * 64, n0w = (w >> 1) * 64;
    __shared__ __align__(16) ushort As[128][40];
    __shared__ __align__(16) ushort Bs[128][40];
    f32x4 acc[4][4] = {};
    const ushort* Ag = wp + (size_t)m0 * CC;
    for (int k0 = 0; k0 < CC; k0 += 32) {
        const ushort* Bg = o_ws + ((size_t)(b * 8 + (k0 >> 6)) * LL + n0) * 64 + (k0 & 63);
        __syncthreads();
        #pragma unroll
        for (int i = 0; i < 2; ++i) {
            int flat = tid + i * 256;
            int row = flat >> 2, ch = (flat & 3) * 8;
            *reinterpret_cast<uint4*>(&As[row][ch]) =
                *reinterpret_cast<const uint4*>(Ag + (size_t)row * CC + k0 + ch);
            *reinterpret_cast<uint4*>(&Bs[row][ch]) =
                *reinterpret_cast<const uint4*>(Bg + (size_t)row * 64 + ch);
        }
        __syncthreads();
        bf16x8 af[4], bfr[4];
        #pragma unroll
        for (int mi = 0; mi < 4; ++mi)
            af[mi] = *reinterpret_cast<const bf16x8*>(&As[m0w + mi*16 + lm][h*8]);
        #pragma unroll
        for (int nj = 0; nj < 4; ++nj)
            bfr[nj] = *reinterpret_cast<const bf16x8*>(&Bs[n0w + nj*16 + lm][h*8]);
        #pragma unroll
        for (int mi = 0; mi < 4; ++mi)
            #pragma unroll
            for (int nj = 0; nj < 4; ++nj)
                acc[mi][nj] = __builtin_amdgcn_mfma_f32_16x16x32_bf16(af[mi], bfr[nj], acc[mi][nj], 0, 0, 0);
    }
    #pragma unroll
    for (int mi = 0; mi < 4; ++mi) {
        int o = m0 + m0w + mi * 16 + h * 4;
        float4 bias = *reinterpret_cast<const float4*>(proj_b + o);
        #pragma unroll
        for (int nj = 0; nj < 4; ++nj) {
            int l = n0 + n0w + nj * 16 + lm;
            size_t xo = (size_t)(b * CC + o) * LL + l;
            out[xo]          = acc[mi][nj][0] + bias.x + x[xo];
            out[xo +   LL]   = acc[mi][nj][1] + bias.y + x[xo +   LL];
            out[xo + 2*LL]   = acc[mi][nj][2] + bias.z + x[xo + 2*LL];
            out[xo + 3*LL]   = acc[mi][nj][3] + bias.w + x[xo + 3*LL];
        }
    }
}

extern "C" void kernel_launch(void* const* d_in, const int* in_sizes, int n_in,
                              void* d_out, int out_size, void* d_ws, size_t ws_size,
                              hipStream_t stream) {
    const float* x      = (const float*)d_in[0];
    const float* norm_w = (const float*)d_in[1];
    const float* norm_b = (const float*)d_in[2];
    const float* qkv_w  = (const float*)d_in[3];
    const float* qkv_b  = (const float*)d_in[4];
    const float* proj_w = (const float*)d_in[5];
    const float* proj_b = (const float*)d_in[6];
    float* out = (float*)d_out;
    char* ws = (char*)d_ws;

    ushort* wq    = (ushort*)(ws);                         // 1536*512 bf16
    ushort* wp    = (ushort*)(ws + 1572864);               // 512*512 bf16
    ushort* hid   = (ushort*)(ws + 2097152);               // (2,4096,512) bf16
    ushort* q_ws  = (ushort*)(ws + 10485760);              // (16,4096,64) bf16
    ushort* k_ws  = (ushort*)(ws + 18874368);              // (16,4096,64) bf16
    ushort* v_ws  = (ushort*)(ws + 27262976);              // (16,64,4096) bf16
    ushort* o_ws  = (ushort*)(ws + 35651584);              // (16,4096,64) bf16
    float2* part  = (float2*)(ws + 44040192);              // 64*8 float2
    float2* stats = (float2*)(ws + 44044288);              // 64 float2

    k_convert<<<dim3(1024), dim3(256), 0, stream>>>(qkv_w, proj_w, wq, wp);
    k_gn_part<<<dim3(64, 8), dim3(256), 0, stream>>>(x, part);
    k_gn_stats<<<dim3(1), dim3(64), 0, stream>>>(part, stats);
    k_gn_apply<<<dim3(16, 64), dim3(256), 0, stream>>>(x, norm_w, norm_b, stats, hid);
    k_qkv<<<dim3(32, 12, 2), dim3(256), 0, stream>>>(wq, hid, qkv_b, q_ws, k_ws, v_ws);
    k_attn<<<dim3(32, 16), dim3(256), 0, stream>>>(q_ws, k_ws, v_ws, o_ws);
    k_proj<<<dim3(32, 4, 2), dim3(256), 0, stream>>>(wp, o_ws, proj_b, x, out);
}

// Round 3
// 174.049 us; speedup vs baseline: 2.9591x; 1.2964x over previous
//
#include <hip/hip_runtime.h>
#include <hip/hip_bf16.h>

// AttentionBlock: x(2,512,64,64) fp32 -> GN(32 groups) -> QKV(1536x512) ->
// 8-head attention (L=4096, ch=64) -> proj(512x512) -> +x.
// All GEMM/attention math in bf16 MFMA (16x16x32), fp32 accumulate.
// Attention uses swapped QK^T (S^T = K·Q^T) so softmax is per-lane scalar,
// P->B-frag redistribution via v_cvt_pk_bf16_f32 + v_permlane{16,32}_swap.

typedef __attribute__((ext_vector_type(8))) short bf16x8;
typedef __attribute__((ext_vector_type(4))) float f32x4;

#define LL 4096
#define CC 512

__device__ __forceinline__ ushort f2bf(float f) {
    union { float f; unsigned u; } v; v.f = f;
    unsigned u = v.u;
    u += 0x7fffu + ((u >> 16) & 1u);   // round-to-nearest-even
    return (ushort)(u >> 16);
}

// butterfly max across lanes +-16 / +-32 via gfx950 permlane swaps (VALU pipe)
__device__ __forceinline__ float bfly_max16(float x) {
    int a = __float_as_int(x), b = a;
    asm("v_permlane16_swap_b32 %0, %1" : "+v"(a), "+v"(b));
    return fmaxf(__int_as_float(a), __int_as_float(b));
}
__device__ __forceinline__ float bfly_max32(float x) {
    int a = __float_as_int(x), b = a;
    asm("v_permlane32_swap_b32 %0, %1" : "+v"(a), "+v"(b));
    return fmaxf(__int_as_float(a), __int_as_float(b));
}
__device__ __forceinline__ uint cvt_pk_bf16(float lo, float hi) {
    uint r;
    asm("v_cvt_pk_bf16_f32 %0, %1, %2" : "=v"(r) : "v"(lo), "v"(hi));
    return r;
}

// ---------------- K0: fp32 weights -> bf16 ----------------
__global__ __launch_bounds__(256) void k_convert(
        const float* __restrict__ qkv_w, const float* __restrict__ proj_w,
        ushort* __restrict__ wq, ushort* __restrict__ wp) {
    const int NQ = 1536 * 512;
    int base = (blockIdx.x * 256 + threadIdx.x) * 4;
    const float* src; ushort* dst; int off;
    if (base < NQ) { src = qkv_w; dst = wq; off = base; }
    else           { src = proj_w; dst = wp; off = base - NQ; }
    float4 v = *reinterpret_cast<const float4*>(src + off);
    ushort4 o;
    o.x = f2bf(v.x); o.y = f2bf(v.y); o.z = f2bf(v.z); o.w = f2bf(v.w);
    *reinterpret_cast<ushort4*>(dst + off) = o;
}

// ---------------- K1a: GN partial sums ----------------
__global__ __launch_bounds__(256) void k_gn_part(
        const float* __restrict__ x, float2* __restrict__ part) {
    int bg = blockIdx.x, sl = blockIdx.y;
    const float4* xg = reinterpret_cast<const float4*>(x + (size_t)bg * 65536) + sl * 2048;
    float s = 0.f, ss = 0.f;
    for (int i = threadIdx.x; i < 2048; i += 256) {
        float4 v = xg[i];
        s  += v.x + v.y + v.z + v.w;
        ss += v.x*v.x + v.y*v.y + v.z*v.z + v.w*v.w;
    }
    #pragma unroll
    for (int m = 32; m; m >>= 1) { s += __shfl_xor(s, m); ss += __shfl_xor(ss, m); }
    __shared__ float red[8];
    int wid = threadIdx.x >> 6;
    if ((threadIdx.x & 63) == 0) { red[wid*2] = s; red[wid*2+1] = ss; }
    __syncthreads();
    if (threadIdx.x == 0) {
        s  = red[0] + red[2] + red[4] + red[6];
        ss = red[1] + red[3] + red[5] + red[7];
        part[bg * 8 + sl] = make_float2(s, ss);
    }
}

// ---------------- K1b: finalize stats ----------------
__global__ void k_gn_stats(const float2* __restrict__ part, float2* __restrict__ stats) {
    int i = threadIdx.x;  // 0..63
    float s = 0.f, ss = 0.f;
    #pragma unroll
    for (int j = 0; j < 8; ++j) { float2 p = part[i*8 + j]; s += p.x; ss += p.y; }
    float mean = s * (1.f/65536.f);
    float var  = ss * (1.f/65536.f) - mean*mean;
    stats[i] = make_float2(mean, rsqrtf(var + 1e-5f));
}

// ---------------- K1c: apply GN, write hid as (b, l, c) bf16 ----------------
__global__ __launch_bounds__(256) void k_gn_apply(
        const float* __restrict__ x, const float* __restrict__ gamma,
        const float* __restrict__ beta, const float2* __restrict__ stats,
        ushort* __restrict__ hid) {
    int bg = blockIdx.y;
    int b = bg >> 5, c0 = (bg & 31) * 16;
    int l0 = blockIdx.x * 256;
    float2 st = stats[bg];
    __shared__ __align__(16) ushort tile[16][256];
    int tid = threadIdx.x;
    const float* xg = x + (size_t)(b * CC + c0) * LL;
    #pragma unroll
    for (int sub = 0; sub < 4; ++sub) {
        int r = sub * 4 + (tid >> 6);
        int c4 = (tid & 63) * 4;
        float4 v = *reinterpret_cast<const float4*>(xg + (size_t)r * LL + l0 + c4);
        float ga = gamma[c0 + r] * st.y;
        float be = beta[c0 + r] - st.x * ga;
        tile[r][c4+0] = f2bf(v.x * ga + be);
        tile[r][c4+1] = f2bf(v.y * ga + be);
        tile[r][c4+2] = f2bf(v.z * ga + be);
        tile[r][c4+3] = f2bf(v.w * ga + be);
    }
    __syncthreads();
    union { ushort u[16]; uint4 q[2]; } pk;
    #pragma unroll
    for (int r = 0; r < 16; ++r) pk.u[r] = tile[r][tid];
    ushort* dst = hid + ((size_t)b * LL + l0 + tid) * CC + c0;
    *reinterpret_cast<uint4*>(dst)     = pk.q[0];
    *reinterpret_cast<uint4*>(dst + 8) = pk.q[1];
}

// ---------------- K2: QKV GEMM ----------------
// Q scale folds 0.125 (=ch^-0.5) AND log2(e) so attention exp is bare v_exp_f32.
#define QSCALE 0.18033688011112042f   // 0.125 * log2(e)
__global__ __launch_bounds__(256) void k_qkv(
        const ushort* __restrict__ wq, const ushort* __restrict__ hid,
        const float* __restrict__ qkv_b,
        ushort* __restrict__ q_ws, ushort* __restrict__ k_ws, ushort* __restrict__ v_ws) {
    int b = blockIdx.z;
    int n0 = blockIdx.x * 128;
    int m0 = blockIdx.y * 128;
    int tid = threadIdx.x;
    int w = tid >> 6, lane = tid & 63, h = lane >> 4, lm = lane & 15;
    int m0w = (w & 1) * 64, n0w = (w >> 1) * 64;
    __shared__ __align__(16) ushort As[128][40];
    __shared__ __align__(16) ushort Bs[128][40];
    f32x4 acc[4][4] = {};
    const ushort* Ag = wq + (size_t)m0 * CC;
    const ushort* Bg = hid + (size_t)(b * LL + n0) * CC;
    for (int k0 = 0; k0 < CC; k0 += 32) {
        __syncthreads();
        #pragma unroll
        for (int i = 0; i < 2; ++i) {
            int flat = tid + i * 256;
            int row = flat >> 2, ch = (flat & 3) * 8;
            *reinterpret_cast<uint4*>(&As[row][ch]) =
                *reinterpret_cast<const uint4*>(Ag + (size_t)row * CC + k0 + ch);
            *reinterpret_cast<uint4*>(&Bs[row][ch]) =
                *reinterpret_cast<const uint4*>(Bg + (size_t)row * CC + k0 + ch);
        }
        __syncthreads();
        bf16x8 af[4], bfr[4];
        #pragma unroll
        for (int mi = 0; mi < 4; ++mi)
            af[mi] = *reinterpret_cast<const bf16x8*>(&As[m0w + mi*16 + lm][h*8]);
        #pragma unroll
        for (int nj = 0; nj < 4; ++nj)
            bfr[nj] = *reinterpret_cast<const bf16x8*>(&Bs[n0w + nj*16 + lm][h*8]);
        #pragma unroll
        for (int mi = 0; mi < 4; ++mi)
            #pragma unroll
            for (int nj = 0; nj < 4; ++nj)
                acc[mi][nj] = __builtin_amdgcn_mfma_f32_16x16x32_bf16(af[mi], bfr[nj], acc[mi][nj], 0, 0, 0);
    }
    #pragma unroll
    for (int mi = 0; mi < 4; ++mi) {
        int o_base = m0 + m0w + mi * 16 + h * 4;
        float4 bias = *reinterpret_cast<const float4*>(qkv_b + o_base);
        int head = o_base / 192;
        int rem  = o_base - head * 192;
        int part = rem >> 6;
        int ch   = rem & 63;
        #pragma unroll
        for (int nj = 0; nj < 4; ++nj) {
            int l = n0 + n0w + nj * 16 + lm;
            float v0 = acc[mi][nj][0] + bias.x;
            float v1 = acc[mi][nj][1] + bias.y;
            float v2 = acc[mi][nj][2] + bias.z;
            float v3 = acc[mi][nj][3] + bias.w;
            if (part == 0) {
                ushort4 pk;
                pk.x = f2bf(v0 * QSCALE); pk.y = f2bf(v1 * QSCALE);
                pk.z = f2bf(v2 * QSCALE); pk.w = f2bf(v3 * QSCALE);
                *reinterpret_cast<ushort4*>(q_ws + ((size_t)(b*8 + head) * LL + l) * 64 + ch) = pk;
            } else if (part == 1) {
                ushort4 pk;
                pk.x = f2bf(v0); pk.y = f2bf(v1); pk.z = f2bf(v2); pk.w = f2bf(v3);
                *reinterpret_cast<ushort4*>(k_ws + ((size_t)(b*8 + head) * LL + l) * 64 + ch) = pk;
            } else {
                ushort* vp = v_ws + ((size_t)(b*8 + head) * 64 + ch) * LL + l;
                vp[0] = f2bf(v0); vp[LL] = f2bf(v1); vp[2*LL] = f2bf(v2); vp[3*LL] = f2bf(v3);
            }
        }
    }
}

// ---------------- K3: flash attention v3 (in-register softmax) ----------------
// grid (32 q-blocks, 16 bh); 4 waves/block; wave owns 32 queries (2 q-tiles).
// S^T = mfma(K, Q): lane holds q = lane&15 for ALL its S values -> softmax
// state is per-lane scalar. kv-reduce: in-lane fmax tree + permlane butterflies.
// P -> PV B-frag: cvt_pk_bf16 pairs + permlane32/16 swaps (no LDS round-trip).
// Row-sum via constant ones-A-frag MFMA (denominator rides in accO[.][4]).
__global__ __launch_bounds__(256) void k_attn(
        const ushort* __restrict__ q_ws, const ushort* __restrict__ k_ws,
        const ushort* __restrict__ v_ws, ushort* __restrict__ o_ws) {
    int bh = blockIdx.y;
    int tid = threadIdx.x;
    int w = tid >> 6, lane = tid & 63, h = lane >> 4, lm = lane & 15;
    int t0 = blockIdx.x * 128 + w * 32;

    __shared__ __align__(16) ushort Ks [2][64][72];   // [kv][c]
    __shared__ __align__(16) ushort Vts[2][64][72];   // [d][kv]

    // Q fragments (B-operand now): q = t0+qt*16+lm, c = kc*32+h*8
    bf16x8 bQ[2][2];
    {
        const ushort* qp = q_ws + ((size_t)bh * LL + t0 + lm) * 64 + h * 8;
        bQ[0][0] = *reinterpret_cast<const bf16x8*>(qp);
        bQ[0][1] = *reinterpret_cast<const bf16x8*>(qp + 32);
        bQ[1][0] = *reinterpret_cast<const bf16x8*>(qp + 16 * 64);
        bQ[1][1] = *reinterpret_cast<const bf16x8*>(qp + 16 * 64 + 32);
    }
    // constant ones A-frag: row(=lm)==0 -> 1.0 : accumulates softmax denominator
    bf16x8 aOnes;
    {
        short v = (lm == 0) ? (short)0x3F80 : (short)0;
        #pragma unroll
        for (int j = 0; j < 8; ++j) aOnes[j] = v;
    }

    int srow = lane >> 3, scol = (lane & 7) * 8;   // staging: 16 rows/wave, 16B chunks
    const ushort* kgp = k_ws + ((size_t)bh * LL + w * 16 + srow) * 64 + scol;
    const ushort* vgp = v_ws + ((size_t)bh * 64 + w * 16 + srow) * LL + scol;
    uint4 kr0, kr1, vr0, vr1;
    auto issue = [&]() {
        kr0 = *reinterpret_cast<const uint4*>(kgp);
        kr1 = *reinterpret_cast<const uint4*>(kgp + 8 * 64);
        vr0 = *reinterpret_cast<const uint4*>(vgp);
        vr1 = *reinterpret_cast<const uint4*>(vgp + 8 * LL);
        kgp += 64 * 64;   // next 64 kv rows
        vgp += 64;        // next 64 kv cols
    };
    issue();

    float mr[2] = {-1e30f, -1e30f};
    f32x4 accO[2][5] = {};   // [qt][nj]; nj=4 = denominator tile

    for (int t = 0; t < 64; ++t) {
        int p = t & 1;
        {   // commit staged tile t into buf p
            int row = w * 16 + srow;
            *reinterpret_cast<uint4*>(&Ks [p][row    ][scol]) = kr0;
            *reinterpret_cast<uint4*>(&Ks [p][row + 8][scol]) = kr1;
            *reinterpret_cast<uint4*>(&Vts[p][row    ][scol]) = vr0;
            *reinterpret_cast<uint4*>(&Vts[p][row + 8][scol]) = vr1;
        }
        if (t < 63) issue();   // stays in flight across the whole compute phase
        __syncthreads();

        // ---- S^T[kv][q] = mfma(K, Q): lane: q=lm, kv = ss*16 + h*4 + r ----
        f32x4 sf[2][4] = {};
        __builtin_amdgcn_s_setprio(1);
        #pragma unroll
        for (int ss = 0; ss < 4; ++ss)
            #pragma unroll
            for (int kc = 0; kc < 2; ++kc) {
                bf16x8 aK = *reinterpret_cast<const bf16x8*>(&Ks[p][ss*16 + lm][kc*32 + h*8]);
                sf[0][ss] = __builtin_amdgcn_mfma_f32_16x16x32_bf16(aK, bQ[0][kc], sf[0][ss], 0, 0, 0);
                sf[1][ss] = __builtin_amdgcn_mfma_f32_16x16x32_bf16(aK, bQ[1][kc], sf[1][ss], 0, 0, 0);
            }
        __builtin_amdgcn_s_setprio(0);

        #pragma unroll
        for (int qt = 0; qt < 2; ++qt) {
            // ---- tile max over kv (in-lane 16 values + cross-h butterflies) ----
            float a0 = fmaxf(fmaxf(sf[qt][0][0], sf[qt][0][1]), fmaxf(sf[qt][0][2], sf[qt][0][3]));
            float a1 = fmaxf(fmaxf(sf[qt][1][0], sf[qt][1][1]), fmaxf(sf[qt][1][2], sf[qt][1][3]));
            float a2 = fmaxf(fmaxf(sf[qt][2][0], sf[qt][2][1]), fmaxf(sf[qt][2][2], sf[qt][2][3]));
            float a3 = fmaxf(fmaxf(sf[qt][3][0], sf[qt][3][1]), fmaxf(sf[qt][3][2], sf[qt][3][3]));
            float tm = fmaxf(fmaxf(a0, a1), fmaxf(a2, a3));
            tm = bfly_max16(tm);
            tm = bfly_max32(tm);
            // ---- defer-max: rescale only when max grew past threshold ----
            if (!__all(tm <= mr[qt] + 8.f)) {
                float mn = fmaxf(mr[qt], tm);
                float corr = __builtin_amdgcn_exp2f(mr[qt] - mn);
                mr[qt] = mn;
                #pragma unroll
                for (int nj = 0; nj < 5; ++nj)
                    #pragma unroll
                    for (int r = 0; r < 4; ++r)
                        accO[qt][nj][r] *= corr;
            }
            // ---- P = 2^(S'-m) (log2e pre-folded into Q) ----
            #pragma unroll
            for (int ss = 0; ss < 4; ++ss)
                #pragma unroll
                for (int r = 0; r < 4; ++r)
                    sf[qt][ss][r] = __builtin_amdgcn_exp2f(sf[qt][ss][r] - mr[qt]);

            // ---- P -> B-frag: pack pairs, permlane redistribute ----
            // W[ss][t] = pk(p[ss][2t], p[ss][2t+1]); per kc:
            //   permlane32_swap(A,C); permlane16_swap(A,C) => A=jj0, C=jj2 words
            bf16x8 bP[2];
            #pragma unroll
            for (int kc = 0; kc < 2; ++kc) {
                uint a = cvt_pk_bf16(sf[qt][2*kc  ][0], sf[qt][2*kc  ][1]);
                uint b = cvt_pk_bf16(sf[qt][2*kc  ][2], sf[qt][2*kc  ][3]);
                uint c = cvt_pk_bf16(sf[qt][2*kc+1][0], sf[qt][2*kc+1][1]);
                uint d = cvt_pk_bf16(sf[qt][2*kc+1][2], sf[qt][2*kc+1][3]);
                asm("v_permlane32_swap_b32 %0, %1" : "+v"(a), "+v"(c));
                asm("v_permlane32_swap_b32 %0, %1" : "+v"(b), "+v"(d));
                asm("v_permlane16_swap_b32 %0, %1" : "+v"(a), "+v"(c));
                asm("v_permlane16_swap_b32 %0, %1" : "+v"(b), "+v"(d));
                union { uint u[4]; bf16x8 v; } pw;
                pw.u[0] = a; pw.u[1] = b; pw.u[2] = c; pw.u[3] = d;
                bP[kc] = pw.v;
            }

            // ---- PV: O^T[d][q] += V^T-frag * P-frag; nj=4 via ones-frag ----
            __builtin_amdgcn_s_setprio(1);
            #pragma unroll
            for (int kc = 0; kc < 2; ++kc) {
                #pragma unroll
                for (int nj = 0; nj < 4; ++nj) {
                    bf16x8 aV = *reinterpret_cast<const bf16x8*>(&Vts[p][nj*16 + lm][kc*32 + h*8]);
                    accO[qt][nj] = __builtin_amdgcn_mfma_f32_16x16x32_bf16(aV, bP[kc], accO[qt][nj], 0, 0, 0);
                }
                accO[qt][4] = __builtin_amdgcn_mfma_f32_16x16x32_bf16(aOnes, bP[kc], accO[qt][4], 0, 0, 0);
            }
            __builtin_amdgcn_s_setprio(0);
        }
    }

    // epilogue: denominator for q=lm sits at lane lm (h=0), reg accO[qt][4][0]
    #pragma unroll
    for (int qt = 0; qt < 2; ++qt) {
        float l  = __shfl(accO[qt][4][0], lm);
        float iv = 1.f / l;
        #pragma unroll
        for (int nj = 0; nj < 4; ++nj) {
            ushort4 o4;
            o4.x = f2bf(accO[qt][nj][0] * iv);
            o4.y = f2bf(accO[qt][nj][1] * iv);
            o4.z = f2bf(accO[qt][nj][2] * iv);
            o4.w = f2bf(accO[qt][nj][3] * iv);
            *reinterpret_cast<ushort4*>(
                o_ws + ((size_t)bh * LL + t0 + qt*16 + lm) * 64 + nj*16 + h*4) = o4;
        }
    }
}

// ---------------- K4: proj GEMM + bias + residual ----------------
__global__ __launch_bounds__(256) void k_proj(
        const ushort* __restrict__ wp, const ushort* __restrict__ o_ws,
        const float* __restrict__ proj_b, const float* __restrict__ x,
        float* __restrict__ out) {
    int b = blockIdx.z;
    int n0 = blockIdx.x * 128;
    int m0 = blockIdx.y * 128;
    int tid = threadIdx.x;
    int w = tid >> 6, lane = tid & 63, h = lane >> 4, lm = lane & 15;
    int m0w = (w & 1) * 64, n0w = (w >> 1) * 64;
    __shared__ __align__(16) ushort As[128][40];
    __shared__ __align__(16) ushort Bs[128][40];
    f32x4 acc[4][4] = {};
    const ushort* Ag = wp + (size_t)m0 * CC;
    for (int k0 = 0; k0 < CC; k0 += 32) {
        const ushort* Bg = o_ws + ((size_t)(b * 8 + (k0 >> 6)) * LL + n0) * 64 + (k0 & 63);
        __syncthreads();
        #pragma unroll
        for (int i = 0; i < 2; ++i) {
            int flat = tid + i * 256;
            int row = flat >> 2, ch = (flat & 3) * 8;
            *reinterpret_cast<uint4*>(&As[row][ch]) =
                *reinterpret_cast<const uint4*>(Ag + (size_t)row * CC + k0 + ch);
            *reinterpret_cast<uint4*>(&Bs[row][ch]) =
                *reinterpret_cast<const uint4*>(Bg + (size_t)row * 64 + ch);
        }
        __syncthreads();
        bf16x8 af[4], bfr[4];
        #pragma unroll
        for (int mi = 0; mi < 4; ++mi)
            af[mi] = *reinterpret_cast<const bf16x8*>(&As[m0w + mi*16 + lm][h*8]);
        #pragma unroll
        for (int nj = 0; nj < 4; ++nj)
            bfr[nj] = *reinterpret_cast<const bf16x8*>(&Bs[n0w + nj*16 + lm][h*8]);
        #pragma unroll
        for (int mi = 0; mi < 4; ++mi)
            #pragma unroll
            for (int nj = 0; nj < 4; ++nj)
                acc[mi][nj] = __builtin_amdgcn_mfma_f32_16x16x32_bf16(af[mi], bfr[nj], acc[mi][nj], 0, 0, 0);
    }
    #pragma unroll
    for (int mi = 0; mi < 4; ++mi) {
        int o = m0 + m0w + mi * 16 + h * 4;
        float4 bias = *reinterpret_cast<const float4*>(proj_b + o);
        #pragma unroll
        for (int nj = 0; nj < 4; ++nj) {
            int l = n0 + n0w + nj * 16 + lm;
            size_t xo = (size_t)(b * CC + o) * LL + l;
            out[xo]          = acc[mi][nj][0] + bias.x + x[xo];
            out[xo +   LL]   = acc[mi][nj][1] + bias.y + x[xo +   LL];
            out[xo + 2*LL]   = acc[mi][nj][2] + bias.z + x[xo + 2*LL];
            out[xo + 3*LL]   = acc[mi][nj][3] + bias.w + x[xo + 3*LL];
        }
    }
}

extern "C" void kernel_launch(void* const* d_in, const int* in_sizes, int n_in,
                              void* d_out, int out_size, void* d_ws, size_t ws_size,
                              hipStream_t stream) {
    const float* x      = (const float*)d_in[0];
    const float* norm_w = (const float*)d_in[1];
    const float* norm_b = (const float*)d_in[2];
    const float* qkv_w  = (const float*)d_in[3];
    const float* qkv_b  = (const float*)d_in[4];
    const float* proj_w = (const float*)d_in[5];
    const float* proj_b = (const float*)d_in[6];
    float* out = (float*)d_out;
    char* ws = (char*)d_ws;

    ushort* wq    = (ushort*)(ws);                         // 1536*512 bf16
    ushort* wp    = (ushort*)(ws + 1572864);               // 512*512 bf16
    ushort* hid   = (ushort*)(ws + 2097152);               // (2,4096,512) bf16
    ushort* q_ws  = (ushort*)(ws + 10485760);              // (16,4096,64) bf16
    ushort* k_ws  = (ushort*)(ws + 18874368);              // (16,4096,64) bf16
    ushort* v_ws  = (ushort*)(ws + 27262976);              // (16,64,4096) bf16
    ushort* o_ws  = (ushort*)(ws + 35651584);              // (16,4096,64) bf16
    float2* part  = (float2*)(ws + 44040192);              // 64*8 float2
    float2* stats = (float2*)(ws + 44044288);              // 64 float2

    k_convert<<<dim3(1024), dim3(256), 0, stream>>>(qkv_w, proj_w, wq, wp);
    k_gn_part<<<dim3(64, 8), dim3(256), 0, stream>>>(x, part);
    k_gn_stats<<<dim3(1), dim3(64), 0, stream>>>(part, stats);
    k_gn_apply<<<dim3(16, 64), dim3(256), 0, stream>>>(x, norm_w, norm_b, stats, hid);
    k_qkv<<<dim3(32, 12, 2), dim3(256), 0, stream>>>(wq, hid, qkv_b, q_ws, k_ws, v_ws);
    k_attn<<<dim3(32, 16), dim3(256), 0, stream>>>(q_ws, k_ws, v_ws, o_ws);
    k_proj<<<dim3(32, 4, 2), dim3(256), 0, stream>>>(wp, o_ws, proj_b, x, out);
}